// Round 5
// baseline (2772.885 us; speedup 1.0000x reference)
//
#include <hip/hip_runtime.h>

#define BS 100000
#define BQ 20000          // BS / 5
#define NWG 256           // workgroups in hist/fillA (must match between them)

typedef unsigned long long ull;

__device__ __forceinline__ float relu_(float v) { return fmaxf(v, 0.0f); }

// ================= binning pipeline =================
// fine bucket  = dst >> 7   (128 nodes)   -> NF = ceil(N/128)
// coarse bucket= dst >> 13  (8192 nodes)  -> NC = ceil(N/8192) (64 fine each)
// record (fillA):  [dst&8191 :13][src:19][wbits:32]
// record (fillA2): [dst&127  :7 ][src:19][wbits:32]   (bits 51.., 32.., 0..)

// one pass over dst: fine counts (global) + per-WG coarse counts hist2D[b*NWG+g]
__global__ __launch_bounds__(256) void hist_kernel(
    const int* __restrict__ dst, int E, int NF, int NC,
    int* __restrict__ fineCnt, int* __restrict__ hist2D)
{
    extern __shared__ int lf[];           // NF ints
    int t = threadIdx.x, g = blockIdx.x;
    for (int i = t; i < NF; i += 256) lf[i] = 0;
    __syncthreads();
    int per = (E + NWG - 1) / NWG;
    int lo = g * per, hi = min(lo + per, E);
    for (int i = lo + t; i < hi; i += 256) atomicAdd(&lf[dst[i] >> 7], 1);
    __syncthreads();
    for (int i = t; i < NF; i += 256) { int v = lf[i]; if (v) atomicAdd(&fineCnt[i], v); }
    for (int b = t; b < NC; b += 256) {
        int s = 0, f0 = b * 64, f1 = min(f0 + 64, NF);
        for (int f = f0; f < f1; f++) s += lf[f];
        hist2D[b * NWG + g] = s;
    }
}

// single-block exclusive scan, n <= 16384
__global__ __launch_bounds__(1024) void scan_kernel(
    const int* __restrict__ in, int n, int* __restrict__ out, int writeTotal)
{
    __shared__ int s[1024];
    int t = threadIdx.x;
    int base = t * 16;
    int vals[16];
    int run = 0;
    #pragma unroll
    for (int k = 0; k < 16; k++) {
        int v = (base + k < n) ? in[base + k] : 0;
        vals[k] = run; run += v;
    }
    s[t] = run;
    __syncthreads();
    for (int d = 1; d < 1024; d <<= 1) {
        int x = (t >= d) ? s[t - d] : 0;
        __syncthreads();
        s[t] += x;
        __syncthreads();
    }
    int excl = s[t] - run;
    #pragma unroll
    for (int k = 0; k < 16; k++)
        if (base + k < n) out[base + k] = excl + vals[k];
    if (writeTotal && t == 1023) out[n] = s[1023];
}

// per-WG private sequential streams per coarse bucket: single-owner write frontiers
__global__ __launch_bounds__(256) void fillA_kernel(
    const int* __restrict__ src, const int* __restrict__ dst,
    const float* __restrict__ w, int E, int NC,
    const int* __restrict__ wgbase, ull* __restrict__ tmp)
{
    __shared__ int cur[64];
    int t = threadIdx.x, g = blockIdx.x;
    if (t < NC) cur[t] = wgbase[t * NWG + g];
    __syncthreads();
    int per = (E + NWG - 1) / NWG;
    int lo = g * per, hi = min(lo + per, E);
    for (int i = lo + t; i < hi; i += 256) {
        int d = dst[i];
        int s = src[i];
        float wv = w[i];
        int b = d >> 13;
        int pos = atomicAdd(&cur[b], 1);
        ull rec = (ull)__float_as_uint(wv)
                | ((ull)(unsigned int)s << 32)
                | ((ull)(unsigned int)(d & 8191) << 51);
        tmp[pos] = rec;
    }
}

// one WG per coarse bucket: scatter to fine-bucket regions (1 MB window, single XCD)
__global__ __launch_bounds__(256) void fillA2_kernel(
    const ull* __restrict__ tmp, const int* __restrict__ wgbase,
    const int* __restrict__ fineOff, int E, int NF,
    ull* __restrict__ tmp2)
{
    __shared__ int fcur[64];
    int t = threadIdx.x, b = blockIdx.x;
    int fb0 = b * 64;
    if (t < 64) fcur[t] = fineOff[min(fb0 + t, NF)];
    __syncthreads();
    int lo = wgbase[b * NWG];
    int hi = (b == (int)gridDim.x - 1) ? E : wgbase[(b + 1) * NWG];
    for (int e = lo + t; e < hi; e += 256) {
        ull rec = tmp[e];
        int dl13 = (int)(rec >> 51);
        int f = dl13 >> 7;
        int pos = atomicAdd(&fcur[f], 1);
        ull out = (rec & ((1ULL << 51) - 1)) | ((ull)(unsigned int)(dl13 & 127) << 51);
        tmp2[pos] = out;
    }
}

// ---------------- z = relu(in @ Wl + bl), fused e (32->32) + t (TIN->8) ----------------
template <int RW, int TIN, int TOFF>
__global__ __launch_bounds__(256) void z_kernel(
    const float* __restrict__ in,
    const float* __restrict__ we, const float* __restrict__ be,
    const float* __restrict__ wt, const float* __restrict__ bt,
    float* __restrict__ zcat, int n)
{
    __shared__ float sWe[32 * 32];
    __shared__ float sWt[TIN * 8];
    __shared__ float sBe[32];
    __shared__ float sBt[8];
    for (int i = threadIdx.x; i < 32 * 32; i += 256) sWe[i] = we[i];
    for (int i = threadIdx.x; i < TIN * 8; i += 256) sWt[i] = wt[i];
    if (threadIdx.x < 32) sBe[threadIdx.x] = be[threadIdx.x];
    if (threadIdx.x < 8)  sBt[threadIdx.x] = bt[threadIdx.x];
    __syncthreads();

    int node = blockIdx.x * 256 + threadIdx.x;
    if (node >= n) return;

    float row[RW];
    {
        const float4* rp = (const float4*)(in + (size_t)node * RW);
        #pragma unroll
        for (int q = 0; q < RW / 4; q++) {
            float4 v = rp[q];
            row[4*q] = v.x; row[4*q+1] = v.y; row[4*q+2] = v.z; row[4*q+3] = v.w;
        }
    }

    float accE[32];
    #pragma unroll
    for (int j = 0; j < 32; j++) accE[j] = sBe[j];
    #pragma unroll
    for (int i = 0; i < 32; i++) {
        float v = row[i];
        #pragma unroll
        for (int j = 0; j < 32; j++) accE[j] = fmaf(v, sWe[i * 32 + j], accE[j]);
    }

    float accT[8];
    #pragma unroll
    for (int j = 0; j < 8; j++) accT[j] = sBt[j];
    #pragma unroll
    for (int i = 0; i < TIN; i++) {
        float v = row[TOFF + i];
        #pragma unroll
        for (int j = 0; j < 8; j++) accT[j] = fmaf(v, sWt[i * 8 + j], accT[j]);
    }

    float4* zv = (float4*)(zcat + (size_t)node * 40);
    #pragma unroll
    for (int q = 0; q < 8; q++)
        zv[q] = make_float4(relu_(accE[4*q]), relu_(accE[4*q+1]),
                            relu_(accE[4*q+2]), relu_(accE[4*q+3]));
    zv[8] = make_float4(relu_(accT[0]), relu_(accT[1]), relu_(accT[2]), relu_(accT[3]));
    zv[9] = make_float4(relu_(accT[4]), relu_(accT[5]), relu_(accT[6]), relu_(accT[7]));
}

// ---------------- fused aggregate (LDS atomics per fine bucket) + finalize ----------------
template <int RW, int TIN, int TOFF>
__global__ __launch_bounds__(256) void finagg_kernel(
    const float* __restrict__ in,        // node features, stride RW
    const float* __restrict__ zcat,      // N x 40
    const ull* __restrict__ tmp2,        // fine-binned records
    const int* __restrict__ fineOff,
    const float* __restrict__ wre, const float* __restrict__ bre,   // 64 x 32, 32
    const float* __restrict__ wrt, const float* __restrict__ brt,   // (TIN+8) x 8, 8
    float* __restrict__ outbuf, int nLimit)
{
    __shared__ float sWe[64 * 32];
    __shared__ float sWt[(TIN + 8) * 8];
    __shared__ float sBe[32];
    __shared__ float sBt[8];
    __shared__ float agg[128][41];
    int t = threadIdx.x;
    for (int i = t; i < 64 * 32; i += 256) sWe[i] = wre[i];
    for (int i = t; i < (TIN + 8) * 8; i += 256) sWt[i] = wrt[i];
    if (t < 32) sBe[t] = bre[t];
    if (t < 8)  sBt[t] = brt[t];
    for (int i = t; i < 128 * 41; i += 256) ((float*)agg)[i] = 0.0f;
    __syncthreads();

    int gf = blockIdx.x;
    int e0 = fineOff[gf], e1 = fineOff[gf + 1];
    for (int e = e0 + t; e < e1; e += 256) {
        ull rec = tmp2[e];
        float wv = __uint_as_float((unsigned int)(rec & 0xFFFFFFFFull));
        int sidx = (int)((rec >> 32) & 0x7FFFFull);
        int dl   = (int)((rec >> 51) & 127ull);
        const float4* zp = (const float4*)(zcat + (size_t)sidx * 40);
        #pragma unroll
        for (int q = 0; q < 10; q++) {
            float4 v = zp[q];
            atomicAdd(&agg[dl][4*q+0], wv * v.x);
            atomicAdd(&agg[dl][4*q+1], wv * v.y);
            atomicAdd(&agg[dl][4*q+2], wv * v.z);
            atomicAdd(&agg[dl][4*q+3], wv * v.w);
        }
        atomicAdd(&agg[dl][40], wv);
    }
    __syncthreads();

    if (t >= 128) return;
    int node = gf * 128 + t;
    if (node >= nLimit) return;

    float inv = 1.0f / (1.0f + agg[t][40]);
    float acc[40];
    #pragma unroll
    for (int j = 0; j < 40; j++) acc[j] = agg[t][j] * inv;

    float row[RW];
    {
        const float4* rp = (const float4*)(in + (size_t)node * RW);
        #pragma unroll
        for (int q = 0; q < RW / 4; q++) {
            float4 v = rp[q];
            row[4*q] = v.x; row[4*q+1] = v.y; row[4*q+2] = v.z; row[4*q+3] = v.w;
        }
    }

    float* op = outbuf + (size_t)node * 40;

    // e-part: [row(0:32), aggE(32)] @ We(64x32) + be
    {
        float o[32];
        #pragma unroll
        for (int j = 0; j < 32; j++) o[j] = sBe[j];
        #pragma unroll
        for (int i = 0; i < 32; i++) {
            float v = row[i];
            #pragma unroll
            for (int j = 0; j < 32; j++) o[j] = fmaf(v, sWe[i * 32 + j], o[j]);
        }
        #pragma unroll
        for (int i = 0; i < 32; i++) {
            float v = acc[i];
            #pragma unroll
            for (int j = 0; j < 32; j++) o[j] = fmaf(v, sWe[(32 + i) * 32 + j], o[j]);
        }
        float4* ov = (float4*)op;
        #pragma unroll
        for (int q = 0; q < 8; q++)
            ov[q] = make_float4(relu_(o[4*q]), relu_(o[4*q+1]), relu_(o[4*q+2]), relu_(o[4*q+3]));
    }

    // t-part: [row(TOFF:TOFF+TIN), aggT(8)] @ Wt((TIN+8)x8) + bt
    {
        float ot[8];
        #pragma unroll
        for (int j = 0; j < 8; j++) ot[j] = sBt[j];
        #pragma unroll
        for (int i = 0; i < TIN; i++) {
            float v = row[TOFF + i];
            #pragma unroll
            for (int j = 0; j < 8; j++) ot[j] = fmaf(v, sWt[i * 8 + j], ot[j]);
        }
        #pragma unroll
        for (int i = 0; i < 8; i++) {
            float v = acc[32 + i];
            #pragma unroll
            for (int j = 0; j < 8; j++) ot[j] = fmaf(v, sWt[(TIN + i) * 8 + j], ot[j]);
        }
        float4* ov = (float4*)op;
        ov[8] = make_float4(relu_(ot[0]), relu_(ot[1]), relu_(ot[2]), relu_(ot[3]));
        ov[9] = make_float4(relu_(ot[4]), relu_(ot[5]), relu_(ot[6]), relu_(ot[7]));
    }
}

// ---------------- loss ----------------

__device__ __forceinline__ void load40(const float* p, float* r) {
    const float4* v = (const float4*)p;
    #pragma unroll
    for (int q = 0; q < 10; q++) {
        float4 t = v[q];
        r[4*q] = t.x; r[4*q+1] = t.y; r[4*q+2] = t.z; r[4*q+3] = t.w;
    }
}

__device__ __forceinline__ float dot40(const float* a, const float* b) {
    float s = 0.0f;
    #pragma unroll
    for (int d = 0; d < 40; d++) s = fmaf(a[d], b[d], s);
    return s;
}

__device__ __forceinline__ void softmax5(const float l[5], float q[5]) {
    float m = l[0];
    #pragma unroll
    for (int c = 1; c < 5; c++) m = fmaxf(m, l[c]);
    float s = 0.0f;
    #pragma unroll
    for (int c = 0; c < 5; c++) { q[c] = expf(l[c] - m); s += q[c]; }
    float inv = 1.0f / s;
    #pragma unroll
    for (int c = 0; c < 5; c++) q[c] *= inv;
}

__device__ __forceinline__ float ent5(const float q[5]) {
    float e = 0.0f;
    #pragma unroll
    for (int c = 0; c < 5; c++) e += q[c] * logf(q[c] + 1e-20f);
    return e;
}

__device__ __forceinline__ float dot5(const float* a, const float* b) {
    float s = 0.0f;
    #pragma unroll
    for (int c = 0; c < 5; c++) s += a[c] * b[c];
    return s;
}

__global__ __launch_bounds__(256) void loss_kernel(
    const float* __restrict__ emb,       // BQ x 5 x 40
    const float* __restrict__ cent,      // 5 x 32
    const float* __restrict__ cent_t,    // 5 x 8
    float* __restrict__ out)
{
    __shared__ float sC[5 * 40];
    for (int i = threadIdx.x; i < 200; i += 256) {
        int c = i / 40, d = i % 40;
        sC[i] = (d < 32) ? cent[c * 32 + d] : cent_t[c * 8 + (d - 32)];
    }
    __syncthreads();

    int i = blockIdx.x * 256 + threadIdx.x;
    float contrib = 0.0f;
    if (i < BQ) {
        const float* base = emb + (size_t)i * 200;

        float ctr[40];
        load40(base, ctr);
        float l[5];
        #pragma unroll
        for (int c = 0; c < 5; c++) l[c] = dot40(ctr, sC + c * 40);
        float qc[5];
        softmax5(l, qc);
        float ent = ent5(qc);

        float rowv[40];
        load40(base + 40, rowv);
        float pd = dot40(ctr, rowv);
        #pragma unroll
        for (int c = 0; c < 5; c++) l[c] = dot40(rowv, sC + c * 40);
        float qp[5];
        softmax5(l, qp);
        float cpd = dot5(qc, qp);
        ent += ent5(qp);

        float nd = -1e30f, cnd = -1e30f;
        #pragma unroll
        for (int k = 0; k < 3; k++) {
            load40(base + (2 + k) * 40, rowv);
            nd = fmaxf(nd, dot40(ctr, rowv));
            #pragma unroll
            for (int c = 0; c < 5; c++) l[c] = dot40(rowv, sC + c * 40);
            float qn[5];
            softmax5(l, qn);
            cnd = fmaxf(cnd, dot5(qc, qn));
            ent += ent5(qn);
        }

        float mm  = fmaxf(nd - pd + 1.0f, 0.0f);
        float cmm = fmaxf(cnd - cpd + 1.0f, 0.0f);
        contrib = (mm + cmm) * (1.0f / (float)BQ) + 0.01f * (1.0f / (float)BS) * ent;
    }

    #pragma unroll
    for (int off = 32; off > 0; off >>= 1) contrib += __shfl_down(contrib, off);
    if ((threadIdx.x & 63) == 0) atomicAdd(out, contrib);
}

// ---------------- launch ----------------

extern "C" void kernel_launch(void* const* d_in, const int* in_sizes, int n_in,
                              void* d_out, int out_size, void* d_ws, size_t ws_size,
                              hipStream_t stream) {
    const float* x      = (const float*)d_in[0];
    const float* weight = (const float*)d_in[1];
    const float* e_w1l  = (const float*)d_in[2];
    const float* e_b1l  = (const float*)d_in[3];
    const float* e_w1r  = (const float*)d_in[4];
    const float* e_b1r  = (const float*)d_in[5];
    const float* e_w2l  = (const float*)d_in[6];
    const float* e_b2l  = (const float*)d_in[7];
    const float* e_w2r  = (const float*)d_in[8];
    const float* e_b2r  = (const float*)d_in[9];
    const float* t_w1l  = (const float*)d_in[10];
    const float* t_b1l  = (const float*)d_in[11];
    const float* t_w1r  = (const float*)d_in[12];
    const float* t_b1r  = (const float*)d_in[13];
    const float* t_w2l  = (const float*)d_in[14];
    const float* t_b2l  = (const float*)d_in[15];
    const float* t_w2r  = (const float*)d_in[16];
    const float* t_b2r  = (const float*)d_in[17];
    const float* cent   = (const float*)d_in[18];
    const float* cent_t = (const float*)d_in[19];
    const int*   eidx   = (const int*)d_in[20];

    const int E = in_sizes[20] / 2;
    const int N = in_sizes[0] / 32;
    const int* srcI = eidx;
    const int* dstI = eidx + E;
    float* out = (float*)d_out;

    const int NF = (N + 127) >> 7;     // 3907 fine buckets (128 nodes)
    const int NC = (N + 8191) >> 13;   // 62 coarse buckets (8192 nodes)

    char* p = (char*)d_ws;
    auto alloc = [&](size_t bytes) -> char* {
        char* r = p;
        p += (bytes + 255) & ~(size_t)255;
        return r;
    };
    float* zcat   = (float*)alloc((size_t)N * 40 * 4);      // 80 MB (also aliases tmp)
    float* hcat   = (float*)alloc((size_t)N * 40 * 4);      // 80 MB
    float* emb    = (float*)alloc((size_t)BS * 40 * 4);     // 16 MB
    ull*   tmp2   = (ull*)alloc((size_t)E * 8);             // 64 MB (fine-binned records)
    int*   fineCnt= (int*)alloc((size_t)NF * 4);
    int*   fineOff= (int*)alloc((size_t)(NF + 1) * 4);
    int*   hist2D = (int*)alloc((size_t)NC * NWG * 4);
    int*   wgbase = (int*)alloc((size_t)(NC * NWG + 1) * 4);
    // coarse tmp aliases zcat: dead before z_kernel writes zcat
    ull*   tmp    = (ull*)zcat;
    (void)ws_size;

    hipMemsetAsync(fineCnt, 0, (size_t)NF * 4, stream);
    hipMemsetAsync(d_out, 0, sizeof(float), stream);

    // binning
    hist_kernel<<<NWG, 256, (size_t)NF * 4, stream>>>(dstI, E, NF, NC, fineCnt, hist2D);
    scan_kernel<<<1, 1024, 0, stream>>>(fineCnt, NF, fineOff, 1);
    scan_kernel<<<1, 1024, 0, stream>>>(hist2D, NC * NWG, wgbase, 0);
    fillA_kernel<<<NWG, 256, 0, stream>>>(srcI, dstI, weight, E, NC, wgbase, tmp);
    fillA2_kernel<<<NC, 256, 0, stream>>>(tmp, wgbase, fineOff, E, NF, tmp2);

    const int nb = (N + 255) / 256;
    // layer 1 (input x, 32-wide; t reads cols 0..31)
    z_kernel<32, 32, 0><<<nb, 256, 0, stream>>>(x, e_w1l, e_b1l, t_w1l, t_b1l, zcat, N);
    finagg_kernel<32, 32, 0><<<NF, 256, 0, stream>>>(x, zcat, tmp2, fineOff,
                                                     e_w1r, e_b1r, t_w1r, t_b1r, hcat, N);
    // layer 2 (input hcat, 40-wide; t reads cols 32..39)
    z_kernel<40, 8, 32><<<nb, 256, 0, stream>>>(hcat, e_w2l, e_b2l, t_w2l, t_b2l, zcat, N);
    const int NF2 = (BS + 127) >> 7;   // 782: only buckets covering nodes < BS
    finagg_kernel<40, 8, 32><<<NF2, 256, 0, stream>>>(hcat, zcat, tmp2, fineOff,
                                                      e_w2r, e_b2r, t_w2r, t_b2r, emb, BS);

    loss_kernel<<<(BQ + 255) / 256, 256, 0, stream>>>(emb, cent, cent_t, out);
}

// Round 6
// 1075.732 us; speedup vs baseline: 2.5777x; 2.5777x over previous
//
#include <hip/hip_runtime.h>

#define BS 100000
#define BQ 20000          // BS / 5
#define NWG 512           // workgroups in hist/fillA partition
#define CB  8192          // nodes per coarse bucket

typedef unsigned long long ull;

__device__ __forceinline__ float relu_(float v) { return fmaxf(v, 0.0f); }

// bf16 helpers (RNE pack, cheap unpack)
__device__ __forceinline__ unsigned bpack2(float a, float b) {
    unsigned ua = __float_as_uint(a), ub = __float_as_uint(b);
    ua = (ua + 0x7FFFu + ((ua >> 16) & 1u)) >> 16;
    ub = (ub + 0x7FFFu + ((ub >> 16) & 1u)) >> 16;
    return ua | (ub << 16);
}
__device__ __forceinline__ float blo(unsigned u) { return __uint_as_float(u << 16); }
__device__ __forceinline__ float bhi(unsigned u) { return __uint_as_float(u & 0xFFFF0000u); }

// ================= binning =================
// record: [dst&8191:13 @51][src:19 @32][wbits:32 @0]
// csr rec: [src:19 @32][wbits:32 @0]  (node-sorted)

// per-WG coarse histogram
__global__ __launch_bounds__(256) void hist_kernel(
    const int* __restrict__ dst, int E, int NC, int* __restrict__ hist2D)
{
    __shared__ int lc[64];
    int t = threadIdx.x, g = blockIdx.x;
    if (t < 64) lc[t] = 0;
    __syncthreads();
    int per = (E + NWG - 1) / NWG;
    int lo = g * per, hi = min(lo + per, E);
    for (int i = lo + t; i < hi; i += 256) atomicAdd(&lc[dst[i] >> 13], 1);
    __syncthreads();
    for (int b = t; b < NC; b += 256) hist2D[b * NWG + g] = lc[b];
}

// single-block exclusive scan, n <= 32768
__global__ __launch_bounds__(1024) void scan_kernel(
    const int* __restrict__ in, int n, int* __restrict__ out)
{
    __shared__ int s[1024];
    int t = threadIdx.x;
    int base = t * 32;
    int vals[32];
    int run = 0;
    #pragma unroll
    for (int k = 0; k < 32; k++) {
        int v = (base + k < n) ? in[base + k] : 0;
        vals[k] = run; run += v;
    }
    s[t] = run;
    __syncthreads();
    for (int d = 1; d < 1024; d <<= 1) {
        int x = (t >= d) ? s[t - d] : 0;
        __syncthreads();
        s[t] += x;
        __syncthreads();
    }
    int excl = s[t] - run;
    #pragma unroll
    for (int k = 0; k < 32; k++)
        if (base + k < n) out[base + k] = excl + vals[k];
}

// per-(WG, coarse-bucket) private streams: single-owner write frontiers
__global__ __launch_bounds__(256) void fillA_kernel(
    const int* __restrict__ src, const int* __restrict__ dst,
    const float* __restrict__ w, int E, int NC,
    const int* __restrict__ wgbase, ull* __restrict__ tmp)
{
    __shared__ int cur[64];
    int t = threadIdx.x, g = blockIdx.x;
    if (t < NC) cur[t] = wgbase[t * NWG + g];
    __syncthreads();
    int per = (E + NWG - 1) / NWG;
    int lo = g * per, hi = min(lo + per, E);
    for (int i = lo + t; i < hi; i += 256) {
        int d = dst[i];
        int s = src[i];
        float wv = w[i];
        int b = d >> 13;
        int pos = atomicAdd(&cur[b], 1);
        ull rec = (ull)__float_as_uint(wv)
                | ((ull)(unsigned int)s << 32)
                | ((ull)(unsigned int)(d & (CB - 1)) << 51);
        tmp[pos] = rec;
    }
}

// one WG per coarse bucket: count -> in-LDS scan(8192) -> node-sorted CSR + offsets
__global__ __launch_bounds__(256) void fillA2B_kernel(
    const ull* __restrict__ tmp, const int* __restrict__ wgbase,
    int NC, int N, int E,
    ull* __restrict__ csr, int* __restrict__ offsets)
{
    __shared__ int cnt[CB];
    __shared__ int ssum[256];
    int b = blockIdx.x, t = threadIdx.x;
    int lo = wgbase[b * NWG];
    int hi = (b == NC - 1) ? E : wgbase[(b + 1) * NWG];
    for (int i = t; i < CB; i += 256) cnt[i] = 0;
    __syncthreads();
    for (int e = lo + t; e < hi; e += 256)
        atomicAdd(&cnt[(int)(tmp[e] >> 51)], 1);
    __syncthreads();

    // scan 8192: thread t owns [t*32, t*32+32)
    int base = t * 32;
    int loc[32];
    int run = 0;
    #pragma unroll
    for (int k = 0; k < 32; k++) { loc[k] = run; run += cnt[base + k]; }
    ssum[t] = run;
    __syncthreads();
    for (int d = 1; d < 256; d <<= 1) {
        int x = (t >= d) ? ssum[t - d] : 0;
        __syncthreads();
        ssum[t] += x;
        __syncthreads();
    }
    int excl = ssum[t] - run;
    int nodeBase = b * CB;
    #pragma unroll
    for (int k = 0; k < 32; k++) {
        int off = excl + loc[k];
        int node = nodeBase + base + k;
        if (node < N) offsets[node] = lo + off;
        loc[k] = off;             // keep for cursor writeback
    }
    __syncthreads();              // all reads of cnt done
    #pragma unroll
    for (int k = 0; k < 32; k++) cnt[base + k] = loc[k];
    if (b == NC - 1 && t == 0) offsets[N] = E;
    __syncthreads();

    // pass 2: scatter to node-sorted order (1 MB L2-local window, single owner)
    for (int e = lo + t; e < hi; e += 256) {
        ull rec = tmp[e];
        int dl = (int)(rec >> 51);
        int pos = atomicAdd(&cnt[dl], 1);
        csr[lo + pos] = rec & ((1ULL << 51) - 1);
    }
}

// ---------------- z = relu(in @ Wl + bl) -> packed bf16 rows (80 B, stride 80 B) ----------------
template <int RW, int TIN, int TOFF>
__global__ __launch_bounds__(256) void z_kernel(
    const float* __restrict__ in,
    const float* __restrict__ we, const float* __restrict__ be,   // 32x32, 32
    const float* __restrict__ wt, const float* __restrict__ bt,   // TINx8, 8
    unsigned short* __restrict__ zb, int n)
{
    __shared__ float sWe[32 * 32];
    __shared__ float sWt[TIN * 8];
    __shared__ float sBe[32];
    __shared__ float sBt[8];
    for (int i = threadIdx.x; i < 32 * 32; i += 256) sWe[i] = we[i];
    for (int i = threadIdx.x; i < TIN * 8; i += 256) sWt[i] = wt[i];
    if (threadIdx.x < 32) sBe[threadIdx.x] = be[threadIdx.x];
    if (threadIdx.x < 8)  sBt[threadIdx.x] = bt[threadIdx.x];
    __syncthreads();

    int node = blockIdx.x * 256 + threadIdx.x;
    if (node >= n) return;

    float row[RW];
    {
        const float4* rp = (const float4*)(in + (size_t)node * RW);
        #pragma unroll
        for (int q = 0; q < RW / 4; q++) {
            float4 v = rp[q];
            row[4*q] = v.x; row[4*q+1] = v.y; row[4*q+2] = v.z; row[4*q+3] = v.w;
        }
    }

    float o[40];
    #pragma unroll
    for (int j = 0; j < 32; j++) o[j] = sBe[j];
    #pragma unroll
    for (int i = 0; i < 32; i++) {
        float v = row[i];
        #pragma unroll
        for (int j = 0; j < 32; j++) o[j] = fmaf(v, sWe[i * 32 + j], o[j]);
    }
    #pragma unroll
    for (int j = 0; j < 8; j++) o[32 + j] = sBt[j];
    #pragma unroll
    for (int i = 0; i < TIN; i++) {
        float v = row[TOFF + i];
        #pragma unroll
        for (int j = 0; j < 8; j++) o[32 + j] = fmaf(v, sWt[i * 8 + j], o[32 + j]);
    }

    unsigned u[20];
    #pragma unroll
    for (int q = 0; q < 20; q++)
        u[q] = bpack2(relu_(o[2*q]), relu_(o[2*q+1]));
    uint4* zv = (uint4*)(zb + (size_t)node * 40);   // 80 B, 16-B aligned (80*node)
    #pragma unroll
    for (int q = 0; q < 5; q++)
        zv[q] = make_uint4(u[4*q], u[4*q+1], u[4*q+2], u[4*q+3]);
}

// ---------------- fused aggregate + finalize (thread-per-node, bf16 gather) ----------------
template <int RW, int TIN, int TOFF>
__global__ __launch_bounds__(256) void fin_kernel(
    const float* __restrict__ in,            // node features, stride RW (fp32)
    const unsigned short* __restrict__ zb,   // N x 40 bf16 packed (80 B rows)
    const int* __restrict__ offsets,
    const ull* __restrict__ csr,             // [src:19 @32][w:32 @0]
    const float* __restrict__ wre, const float* __restrict__ bre,   // 64x32, 32
    const float* __restrict__ wrt, const float* __restrict__ brt,   // (TIN+8)x8, 8
    float* __restrict__ outbuf, int n)       // n rows, stride 40 fp32
{
    __shared__ float sWe[64 * 32];
    __shared__ float sWt[(TIN + 8) * 8];
    __shared__ float sBe[32];
    __shared__ float sBt[8];
    for (int i = threadIdx.x; i < 64 * 32; i += 256) sWe[i] = wre[i];
    for (int i = threadIdx.x; i < (TIN + 8) * 8; i += 256) sWt[i] = wrt[i];
    if (threadIdx.x < 32) sBe[threadIdx.x] = bre[threadIdx.x];
    if (threadIdx.x < 8)  sBt[threadIdx.x] = brt[threadIdx.x];
    __syncthreads();

    int node = blockIdx.x * 256 + threadIdx.x;
    if (node >= n) return;

    float acc[40];
    #pragma unroll
    for (int j = 0; j < 40; j++) acc[j] = 0.0f;
    float wsum = 1.0f;

    int e0 = offsets[node];
    int e1 = offsets[node + 1];
    for (int e = e0; e < e1; e++) {
        ull pk = csr[e];
        float w = __uint_as_float((unsigned int)pk);
        int sidx = (int)((pk >> 32) & 0x7FFFFull);
        const uint4* zp = (const uint4*)(zb + (size_t)sidx * 40);
        #pragma unroll
        for (int q = 0; q < 5; q++) {
            uint4 v = zp[q];
            acc[8*q+0] = fmaf(w, blo(v.x), acc[8*q+0]);
            acc[8*q+1] = fmaf(w, bhi(v.x), acc[8*q+1]);
            acc[8*q+2] = fmaf(w, blo(v.y), acc[8*q+2]);
            acc[8*q+3] = fmaf(w, bhi(v.y), acc[8*q+3]);
            acc[8*q+4] = fmaf(w, blo(v.z), acc[8*q+4]);
            acc[8*q+5] = fmaf(w, bhi(v.z), acc[8*q+5]);
            acc[8*q+6] = fmaf(w, blo(v.w), acc[8*q+6]);
            acc[8*q+7] = fmaf(w, bhi(v.w), acc[8*q+7]);
        }
        wsum += w;
    }
    float inv = 1.0f / wsum;
    #pragma unroll
    for (int j = 0; j < 40; j++) acc[j] *= inv;

    float row[RW];
    {
        const float4* rp = (const float4*)(in + (size_t)node * RW);
        #pragma unroll
        for (int q = 0; q < RW / 4; q++) {
            float4 v = rp[q];
            row[4*q] = v.x; row[4*q+1] = v.y; row[4*q+2] = v.z; row[4*q+3] = v.w;
        }
    }

    float* op = outbuf + (size_t)node * 40;

    // e-part: [row(0:32), aggE(32)] @ We(64x32) + be
    {
        float o[32];
        #pragma unroll
        for (int j = 0; j < 32; j++) o[j] = sBe[j];
        #pragma unroll
        for (int i = 0; i < 32; i++) {
            float v = row[i];
            #pragma unroll
            for (int j = 0; j < 32; j++) o[j] = fmaf(v, sWe[i * 32 + j], o[j]);
        }
        #pragma unroll
        for (int i = 0; i < 32; i++) {
            float v = acc[i];
            #pragma unroll
            for (int j = 0; j < 32; j++) o[j] = fmaf(v, sWe[(32 + i) * 32 + j], o[j]);
        }
        float4* ov = (float4*)op;
        #pragma unroll
        for (int q = 0; q < 8; q++)
            ov[q] = make_float4(relu_(o[4*q]), relu_(o[4*q+1]), relu_(o[4*q+2]), relu_(o[4*q+3]));
    }

    // t-part: [row(TOFF:TOFF+TIN), aggT(8)] @ Wt((TIN+8)x8) + bt
    {
        float ot[8];
        #pragma unroll
        for (int j = 0; j < 8; j++) ot[j] = sBt[j];
        #pragma unroll
        for (int i = 0; i < TIN; i++) {
            float v = row[TOFF + i];
            #pragma unroll
            for (int j = 0; j < 8; j++) ot[j] = fmaf(v, sWt[i * 8 + j], ot[j]);
        }
        #pragma unroll
        for (int i = 0; i < 8; i++) {
            float v = acc[32 + i];
            #pragma unroll
            for (int j = 0; j < 8; j++) ot[j] = fmaf(v, sWt[(TIN + i) * 8 + j], ot[j]);
        }
        float4* ov = (float4*)op;
        ov[8] = make_float4(relu_(ot[0]), relu_(ot[1]), relu_(ot[2]), relu_(ot[3]));
        ov[9] = make_float4(relu_(ot[4]), relu_(ot[5]), relu_(ot[6]), relu_(ot[7]));
    }
}

// ---------------- loss ----------------

__device__ __forceinline__ void load40(const float* p, float* r) {
    const float4* v = (const float4*)p;
    #pragma unroll
    for (int q = 0; q < 10; q++) {
        float4 t = v[q];
        r[4*q] = t.x; r[4*q+1] = t.y; r[4*q+2] = t.z; r[4*q+3] = t.w;
    }
}

__device__ __forceinline__ float dot40(const float* a, const float* b) {
    float s = 0.0f;
    #pragma unroll
    for (int d = 0; d < 40; d++) s = fmaf(a[d], b[d], s);
    return s;
}

__device__ __forceinline__ void softmax5(const float l[5], float q[5]) {
    float m = l[0];
    #pragma unroll
    for (int c = 1; c < 5; c++) m = fmaxf(m, l[c]);
    float s = 0.0f;
    #pragma unroll
    for (int c = 0; c < 5; c++) { q[c] = expf(l[c] - m); s += q[c]; }
    float inv = 1.0f / s;
    #pragma unroll
    for (int c = 0; c < 5; c++) q[c] *= inv;
}

__device__ __forceinline__ float ent5(const float q[5]) {
    float e = 0.0f;
    #pragma unroll
    for (int c = 0; c < 5; c++) e += q[c] * logf(q[c] + 1e-20f);
    return e;
}

__device__ __forceinline__ float dot5(const float* a, const float* b) {
    float s = 0.0f;
    #pragma unroll
    for (int c = 0; c < 5; c++) s += a[c] * b[c];
    return s;
}

__global__ __launch_bounds__(256) void loss_kernel(
    const float* __restrict__ emb,       // BQ x 5 x 40
    const float* __restrict__ cent,      // 5 x 32
    const float* __restrict__ cent_t,    // 5 x 8
    float* __restrict__ out)
{
    __shared__ float sC[5 * 40];
    for (int i = threadIdx.x; i < 200; i += 256) {
        int c = i / 40, d = i % 40;
        sC[i] = (d < 32) ? cent[c * 32 + d] : cent_t[c * 8 + (d - 32)];
    }
    __syncthreads();

    int i = blockIdx.x * 256 + threadIdx.x;
    float contrib = 0.0f;
    if (i < BQ) {
        const float* base = emb + (size_t)i * 200;

        float ctr[40];
        load40(base, ctr);
        float l[5];
        #pragma unroll
        for (int c = 0; c < 5; c++) l[c] = dot40(ctr, sC + c * 40);
        float qc[5];
        softmax5(l, qc);
        float ent = ent5(qc);

        float rowv[40];
        load40(base + 40, rowv);
        float pd = dot40(ctr, rowv);
        #pragma unroll
        for (int c = 0; c < 5; c++) l[c] = dot40(rowv, sC + c * 40);
        float qp[5];
        softmax5(l, qp);
        float cpd = dot5(qc, qp);
        ent += ent5(qp);

        float nd = -1e30f, cnd = -1e30f;
        #pragma unroll
        for (int k = 0; k < 3; k++) {
            load40(base + (2 + k) * 40, rowv);
            nd = fmaxf(nd, dot40(ctr, rowv));
            #pragma unroll
            for (int c = 0; c < 5; c++) l[c] = dot40(rowv, sC + c * 40);
            float qn[5];
            softmax5(l, qn);
            cnd = fmaxf(cnd, dot5(qc, qn));
            ent += ent5(qn);
        }

        float mm  = fmaxf(nd - pd + 1.0f, 0.0f);
        float cmm = fmaxf(cnd - cpd + 1.0f, 0.0f);
        contrib = (mm + cmm) * (1.0f / (float)BQ) + 0.01f * (1.0f / (float)BS) * ent;
    }

    #pragma unroll
    for (int off = 32; off > 0; off >>= 1) contrib += __shfl_down(contrib, off);
    if ((threadIdx.x & 63) == 0) atomicAdd(out, contrib);
}

// ---------------- launch ----------------

extern "C" void kernel_launch(void* const* d_in, const int* in_sizes, int n_in,
                              void* d_out, int out_size, void* d_ws, size_t ws_size,
                              hipStream_t stream) {
    const float* x      = (const float*)d_in[0];
    const float* weight = (const float*)d_in[1];
    const float* e_w1l  = (const float*)d_in[2];
    const float* e_b1l  = (const float*)d_in[3];
    const float* e_w1r  = (const float*)d_in[4];
    const float* e_b1r  = (const float*)d_in[5];
    const float* e_w2l  = (const float*)d_in[6];
    const float* e_b2l  = (const float*)d_in[7];
    const float* e_w2r  = (const float*)d_in[8];
    const float* e_b2r  = (const float*)d_in[9];
    const float* t_w1l  = (const float*)d_in[10];
    const float* t_b1l  = (const float*)d_in[11];
    const float* t_w1r  = (const float*)d_in[12];
    const float* t_b1r  = (const float*)d_in[13];
    const float* t_w2l  = (const float*)d_in[14];
    const float* t_b2l  = (const float*)d_in[15];
    const float* t_w2r  = (const float*)d_in[16];
    const float* t_b2r  = (const float*)d_in[17];
    const float* cent   = (const float*)d_in[18];
    const float* cent_t = (const float*)d_in[19];
    const int*   eidx   = (const int*)d_in[20];

    const int E = in_sizes[20] / 2;
    const int N = in_sizes[0] / 32;
    const int* srcI = eidx;
    const int* dstI = eidx + E;
    float* out = (float*)d_out;

    const int NC = (N + CB - 1) / CB;    // 62 coarse buckets

    char* p = (char*)d_ws;
    auto alloc = [&](size_t bytes) -> char* {
        char* r = p;
        p += (bytes + 255) & ~(size_t)255;
        return r;
    };
    // region A: tmp (64 MB) aliased with zb (40 MB) — disjoint lifetimes
    char* regionA = alloc((size_t)E * 8);
    ull*  tmp     = (ull*)regionA;
    unsigned short* zb = (unsigned short*)regionA;
    float* hcat   = (float*)alloc((size_t)N * 40 * 4);        // 80 MB
    float* emb    = (float*)alloc((size_t)BS * 40 * 4);       // 16 MB
    ull*   csr    = (ull*)alloc((size_t)E * 8);               // 64 MB
    int*   offsets= (int*)alloc((size_t)(N + 1) * 4);
    int*   hist2D = (int*)alloc((size_t)NC * NWG * 4);
    int*   wgbase = (int*)alloc((size_t)NC * NWG * 4);
    (void)ws_size;

    hipMemsetAsync(d_out, 0, sizeof(float), stream);

    // binning: coarse per-WG hist -> scan -> single-owner binned tmp -> node-sorted CSR
    hist_kernel<<<NWG, 256, 0, stream>>>(dstI, E, NC, hist2D);
    scan_kernel<<<1, 1024, 0, stream>>>(hist2D, NC * NWG, wgbase);
    fillA_kernel<<<NWG, 256, 0, stream>>>(srcI, dstI, weight, E, NC, wgbase, tmp);
    fillA2B_kernel<<<NC, 256, 0, stream>>>(tmp, wgbase, NC, N, E, csr, offsets);

    const int nb = (N + 255) / 256;
    // layer 1 (input x, 32-wide; t reads cols 0..31)
    z_kernel<32, 32, 0><<<nb, 256, 0, stream>>>(x, e_w1l, e_b1l, t_w1l, t_b1l, zb, N);
    fin_kernel<32, 32, 0><<<nb, 256, 0, stream>>>(x, zb, offsets, csr,
                                                  e_w1r, e_b1r, t_w1r, t_b1r, hcat, N);
    // layer 2 (input hcat, 40-wide; t reads cols 32..39)
    z_kernel<40, 8, 32><<<nb, 256, 0, stream>>>(hcat, e_w2l, e_b2l, t_w2l, t_b2l, zb, N);
    const int nb2 = (BS + 255) / 256;
    fin_kernel<40, 8, 32><<<nb2, 256, 0, stream>>>(hcat, zb, offsets, csr,
                                                   e_w2r, e_b2r, t_w2r, t_b2r, emb, BS);

    loss_kernel<<<(BQ + 255) / 256, 256, 0, stream>>>(emb, cent, cent_t, out);
}